// Round 6
// baseline (221.889 us; speedup 1.0000x reference)
//
#include <hip/hip_runtime.h>

#define B_ 2
#define S_ 2048
#define D_ 1024
#define H_ 16
#define DK_ 64

typedef float f32x4 __attribute__((ext_vector_type(4)));
typedef float f32x16 __attribute__((ext_vector_type(16)));
typedef short bf16x8 __attribute__((ext_vector_type(8)));

static __device__ __forceinline__ unsigned short f2bf(float f) {
  unsigned u = __float_as_uint(f);
  unsigned r = (u + 0x7FFFu + ((u >> 16) & 1u)) >> 16;
  return (unsigned short)r;
}

static __device__ __forceinline__ unsigned cvtpk_bf16(float lo, float hi) {
  unsigned r;
  asm("v_cvt_pk_bf16_f32 %0, %1, %2" : "=v"(r) : "v"(lo), "v"(hi));
  return r;
}

static __device__ __forceinline__ void load16_lds(const void* g, void* lds) {
  __builtin_amdgcn_global_load_lds(
      (const __attribute__((address_space(1))) unsigned int*)g,
      (__attribute__((address_space(3))) unsigned int*)lds, 16, 0, 0);
}

// gather 8 consecutive C-rows of this lane's owned column from crow-scattered
// accumulator regs p[0..7]; returns the 8 bf16 packed (A-frag k-slice).
static __device__ __forceinline__ bf16x8 make_pa8(const float* p, int hi) {
  unsigned x1 = cvtpk_bf16(p[0], p[1]);
  unsigned x2 = cvtpk_bf16(p[2], p[3]);
  unsigned y1 = cvtpk_bf16(p[4], p[5]);
  unsigned y2 = cvtpk_bf16(p[6], p[7]);
  unsigned sx1 = (unsigned)__shfl_xor((int)x1, 32);
  unsigned sx2 = (unsigned)__shfl_xor((int)x2, 32);
  unsigned sy1 = (unsigned)__shfl_xor((int)y1, 32);
  unsigned sy2 = (unsigned)__shfl_xor((int)y2, 32);
  union {
    unsigned u[4];
    bf16x8 v;
  } pa;
  pa.u[0] = hi ? sy1 : x1;
  pa.u[1] = hi ? sy2 : x2;
  pa.u[2] = hi ? y1 : sx1;
  pa.u[3] = hi ? y2 : sx2;
  return pa.v;
}

static __device__ __forceinline__ float tanh_fast(float x) {
  float xc = fminf(fmaxf(x, -9.0f), 9.0f);
  float e = exp2f(xc * 2.88539008177792681472f);  // 2*log2(e)
  return (e - 1.0f) / (e + 1.0f);
}

// ---------------------------------------------------------------------------
// Kernel 1: fused MFMA quantum transform for q, k, v (blockIdx.z selects).
// ---------------------------------------------------------------------------
__global__ __launch_bounds__(256) void quantum_fused(
    const float* __restrict__ xq, const float* __restrict__ xk,
    const float* __restrict__ xv,
    const float* __restrict__ Wq1, const float* __restrict__ bq1,
    const float* __restrict__ Wq2, const float* __restrict__ bq2,
    const float* __restrict__ Wk1, const float* __restrict__ bk1,
    const float* __restrict__ Wk2, const float* __restrict__ bk2,
    const float* __restrict__ Wv1, const float* __restrict__ bv1,
    const float* __restrict__ Wv2, const float* __restrict__ bv2,
    unsigned short* __restrict__ qhb, unsigned short* __restrict__ khb,
    unsigned short* __restrict__ vtb, float qscale) {
  const int tid = threadIdx.x;
  const int w = tid >> 6;
  const int l = tid & 63;
  const int lq = l & 31;
  const int hi = l >> 5;
  const int bh = blockIdx.y;
  const int b = bh >> 4, h = bh & 15;
  const int s0w = blockIdx.x * 128 + w * 32;

  const float* x;
  const float* W1;
  const float* b1;
  const float* W2;
  const float* b2;
  unsigned short* outp;
  float scale = 1.0f;
  int vmode = 0;
  if (blockIdx.z == 0) {
    x = xq; W1 = Wq1; b1 = bq1; W2 = Wq2; b2 = bq2; outp = qhb;
    scale = qscale;
  } else if (blockIdx.z == 1) {
    x = xk; W1 = Wk1; b1 = bk1; W2 = Wk2; b2 = bk2; outp = khb;
  } else {
    x = xv; W1 = Wv1; b1 = bv1; W2 = Wv2; b2 = bv2; outp = vtb;
    vmode = 1;
  }

  bf16x8 w1f[2][4];
#pragma unroll
  for (int ca = 0; ca < 2; ++ca)
#pragma unroll
    for (int kc = 0; kc < 4; ++kc) {
      const float* wp = W1 + (size_t)(kc * 16 + hi * 8) * 64 + ca * 32 + lq;
      union {
        unsigned u[4];
        bf16x8 v;
      } ww;
#pragma unroll
      for (int jj = 0; jj < 4; ++jj)
        ww.u[jj] = cvtpk_bf16(wp[(2 * jj) * 64], wp[(2 * jj + 1) * 64]);
      w1f[ca][kc] = ww.v;
    }

  const float* xrow = x + (((size_t)b * S_ + s0w + lq) * H_ + h) * DK_;
  bf16x8 xf[4];
#pragma unroll
  for (int kc = 0; kc < 4; ++kc) {
    float4 f0 = *(const float4*)(xrow + kc * 16 + hi * 8);
    float4 f1 = *(const float4*)(xrow + kc * 16 + hi * 8 + 4);
    union {
      unsigned u[4];
      bf16x8 v;
    } xx;
    xx.u[0] = cvtpk_bf16(f0.x, f0.y);
    xx.u[1] = cvtpk_bf16(f0.z, f0.w);
    xx.u[2] = cvtpk_bf16(f1.x, f1.y);
    xx.u[3] = cvtpk_bf16(f1.z, f1.w);
    xf[kc] = xx.v;
  }

  f32x16 acc1[2];
#pragma unroll
  for (int ca = 0; ca < 2; ++ca)
#pragma unroll
    for (int r = 0; r < 16; ++r)
      acc1[ca][r] = b1[ca * 32 + (r & 3) + 8 * (r >> 2) + 4 * hi];
#pragma unroll
  for (int kc = 0; kc < 4; ++kc) {
    acc1[0] = __builtin_amdgcn_mfma_f32_32x32x16_bf16(w1f[0][kc], xf[kc], acc1[0], 0, 0, 0);
    acc1[1] = __builtin_amdgcn_mfma_f32_32x32x16_bf16(w1f[1][kc], xf[kc], acc1[1], 0, 0, 0);
  }

  float t0[16], t1[16];
#pragma unroll
  for (int r = 0; r < 16; ++r) {
    t0[r] = tanh_fast(acc1[0][r]);
    t1[r] = tanh_fast(acc1[1][r]);
  }

  bf16x8 af[4];
  af[0] = make_pa8(&t0[0], hi);
  af[1] = make_pa8(&t0[8], hi);
  af[2] = make_pa8(&t1[0], hi);
  af[3] = make_pa8(&t1[8], hi);

  bf16x8 w2f[2][4];
#pragma unroll
  for (int nb = 0; nb < 2; ++nb)
#pragma unroll
    for (int kc = 0; kc < 4; ++kc) {
      const float* wp = W2 + (size_t)(kc * 16 + hi * 8) * 64 + nb * 32 + lq;
      union {
        unsigned u[4];
        bf16x8 v;
      } ww;
#pragma unroll
      for (int jj = 0; jj < 4; ++jj)
        ww.u[jj] = cvtpk_bf16(wp[(2 * jj) * 64], wp[(2 * jj + 1) * 64]);
      w2f[nb][kc] = ww.v;
    }

  f32x16 acc2[2];
#pragma unroll
  for (int nb = 0; nb < 2; ++nb)
#pragma unroll
    for (int r = 0; r < 16; ++r)
      acc2[nb][r] = b2[nb * 32 + (r & 3) + 8 * (r >> 2) + 4 * hi];
#pragma unroll
  for (int kc = 0; kc < 4; ++kc) {
    acc2[0] = __builtin_amdgcn_mfma_f32_32x32x16_bf16(af[kc], w2f[0][kc], acc2[0], 0, 0, 0);
    acc2[1] = __builtin_amdgcn_mfma_f32_32x32x16_bf16(af[kc], w2f[1][kc], acc2[1], 0, 0, 0);
  }

  if (!vmode) {
#pragma unroll
    for (int nb = 0; nb < 2; ++nb)
#pragma unroll
      for (int r = 0; r < 16; ++r) {
        const int s = s0w + (r & 3) + 8 * (r >> 2) + 4 * hi;
        outp[((size_t)bh * S_ + s) * DK_ + nb * 32 + lq] =
            f2bf(acc2[nb][r] * scale);
      }
  } else {
#pragma unroll
    for (int nb = 0; nb < 2; ++nb) {
      float yv[16];
#pragma unroll
      for (int r = 0; r < 16; ++r) yv[r] = acc2[nb][r];
      const size_t rowb = ((size_t)bh * DK_ + nb * 32 + lq) * S_;
      *(bf16x8*)(outp + rowb + s0w + hi * 8) = make_pa8(&yv[0], hi);
      *(bf16x8*)(outp + rowb + s0w + 16 + hi * 8) = make_pa8(&yv[8], hi);
    }
  }
}

// ---------------------------------------------------------------------------
// Kernel 2: MFMA flash attention, swapped-QK^T 32x32x16, in-block K-split.
// 4 waves = 2 pairs; pair p handles keys [p*1024, p*1024+1024) for a 64-row
// q-block; wave within pair handles 32 q-rows. T14 reg-prefetch of next tile.
// Final (m,l,O) merge through LDS. grid (32 bh, 32 q-blocks of 64).
// ---------------------------------------------------------------------------
__global__ __launch_bounds__(256, 4) void attn_kernel(
    const unsigned short* __restrict__ qhb,
    const unsigned short* __restrict__ khb,
    const unsigned short* __restrict__ vtb,
    unsigned short* __restrict__ ctxb) {
  __shared__ __align__(16) unsigned short ks_u[2][64 * 64];  // per-pair K tile
  __shared__ __align__(16) unsigned short vs_u[2][64 * 64];  // per-pair V^T tile

  const int tid = threadIdx.x;
  const int w = tid >> 6;
  const int p = w >> 1;   // K-half
  const int l = tid & 63;
  const int lq = l & 31;
  const int hi = l >> 5;
  const int bh = blockIdx.x;
  const int b = bh >> 4, h = bh & 15;
  const int q0 = blockIdx.y * 64 + (w & 1) * 32;

  // Q fragments for the whole kernel (pre-scaled by 1/8*log2e)
  const unsigned short* qp = qhb + ((size_t)bh * S_ + q0 + lq) * DK_ + hi * 8;
  bf16x8 qf[4];
#pragma unroll
  for (int kc = 0; kc < 4; ++kc) qf[kc] = *(const bf16x8*)(qp + kc * 16);

  f32x16 o0 = {}, o1 = {};
  float m_ = -1e30f, l_ = 0.f;

  // staging roles: 128 threads per pair move the pair's 16KB tile set
  const int kk = (tid & 127) >> 1;  // row 0..63
  const int ch2 = tid & 1;          // 64B-half of the row
  const unsigned short* kgbase = khb + (size_t)bh * S_ * DK_;
  const unsigned short* vgbase = vtb + (size_t)bh * DK_ * S_;
  char* ksP = (char*)&ks_u[p][0];
  char* vsP = (char*)&vs_u[p][0];

  uint4 ra[4], rb[4];

#define LOADKV(TT)                                                            \
  {                                                                           \
    const int tb = p * 1024 + (TT)*64;                                        \
    const uint4* gk =                                                         \
        (const uint4*)(kgbase + (size_t)(tb + kk) * DK_ + ch2 * 32);          \
    ra[0] = gk[0]; ra[1] = gk[1]; ra[2] = gk[2]; ra[3] = gk[3];               \
    const uint4* gv = (const uint4*)(vgbase + (size_t)kk * S_ + tb + ch2 * 32);\
    rb[0] = gv[0]; rb[1] = gv[1]; rb[2] = gv[2]; rb[3] = gv[3];               \
  }

#define WRITEKV()                                                             \
  {                                                                           \
    char* kd = ksP + kk * 128;                                                \
    char* vd = vsP + kk * 128;                                                \
    _Pragma("unroll") for (int j = 0; j < 4; ++j) {                           \
      *(uint4*)(kd + (((ch2 * 4 + j) ^ (kk & 7)) << 4)) = ra[j];              \
      *(uint4*)(vd + (((ch2 * 4 + j) ^ (kk & 7)) << 4)) = rb[j];              \
    }                                                                         \
  }

  LOADKV(0)
  WRITEKV()
  __syncthreads();

  for (int t = 0; t < 16; ++t) {
    if (t < 15) LOADKV(t + 1)  // issue next tile early; drained at barrier

    // ---- QK^T: S^T[k][q=lq] ----
    f32x16 s0 = {}, s1 = {};
#pragma unroll
    for (int kc = 0; kc < 4; ++kc) {
      const int slot = kc * 2 + hi;
      bf16x8 k0 = *(const bf16x8*)(ksP + lq * 128 + ((slot ^ (lq & 7)) << 4));
      bf16x8 k1 = *(const bf16x8*)(ksP + (32 + lq) * 128 + ((slot ^ (lq & 7)) << 4));
      s0 = __builtin_amdgcn_mfma_f32_32x32x16_bf16(k0, qf[kc], s0, 0, 0, 0);
      s1 = __builtin_amdgcn_mfma_f32_32x32x16_bf16(k1, qf[kc], s1, 0, 0, 0);
    }

    // ---- lane-local online softmax with defer-max (THR=8) ----
    float pmax = s0[0];
#pragma unroll
    for (int i = 1; i < 16; ++i) pmax = fmaxf(pmax, s0[i]);
#pragma unroll
    for (int i = 0; i < 16; ++i) pmax = fmaxf(pmax, s1[i]);
    pmax = fmaxf(pmax, __shfl_xor(pmax, 32));

    if (!__all(pmax <= m_ + 8.0f)) {
      const float mnew = fmaxf(m_, pmax);
      const float scl = exp2f(m_ - mnew);
      m_ = mnew;
      l_ *= scl;
#pragma unroll
      for (int r = 0; r < 16; ++r) {
        const float sr = __shfl(scl, ((r & 3) + 8 * (r >> 2)) + 4 * hi);
        o0[r] *= sr;
        o1[r] *= sr;
      }
    }

    // exp2 in place (P values)
#pragma unroll
    for (int i = 0; i < 16; ++i) s0[i] = exp2f(s0[i] - m_);
#pragma unroll
    for (int i = 0; i < 16; ++i) s1[i] = exp2f(s1[i] - m_);
    {
      float t0a = 0.f, t1a = 0.f, t2a = 0.f, t3a = 0.f;
#pragma unroll
      for (int i = 0; i < 16; i += 4) {
        t0a += s0[i] + s1[i];
        t1a += s0[i + 1] + s1[i + 1];
        t2a += s0[i + 2] + s1[i + 2];
        t3a += s0[i + 3] + s1[i + 3];
      }
      float ps = (t0a + t1a) + (t2a + t3a);
      ps += __shfl_xor(ps, 32);
      l_ += ps;
    }

    // ---- P -> A-frags + PV ----
    float pv[8];
    union {
      unsigned u[4];
      bf16x8 v;
    } pa;

#define PV_STEP(SARR, CC, CIDX)                                               \
  {                                                                           \
    _Pragma("unroll") for (int j = 0; j < 8; ++j) pv[j] = SARR[(CC)*8 + j];   \
    pa.v = make_pa8(pv, hi);                                                  \
    const int slot = (CIDX)*2 + hi;                                           \
    bf16x8 v0 = *(const bf16x8*)(vsP + lq * 128 + ((slot ^ (lq & 7)) << 4));  \
    bf16x8 v1 = *(const bf16x8*)(vsP + (32 + lq) * 128 + ((slot ^ (lq & 7)) << 4)); \
    o0 = __builtin_amdgcn_mfma_f32_32x32x16_bf16(pa.v, v0, o0, 0, 0, 0);      \
    o1 = __builtin_amdgcn_mfma_f32_32x32x16_bf16(pa.v, v1, o1, 0, 0, 0);      \
  }

    PV_STEP(s0, 0, 0)
    PV_STEP(s0, 1, 1)
    PV_STEP(s1, 0, 2)
    PV_STEP(s1, 1, 3)
#undef PV_STEP

    __syncthreads();  // compute done; prefetch loads drained here
    if (t < 15) WRITEKV()
    __syncthreads();  // new tile visible
  }
#undef LOADKV
#undef WRITEKV

  // ---- cross-pair merge through LDS ----
  float* ksf = (float*)&ks_u[0][0];  // [64][64] fp32: pair-1 O partial
  float* mlf = (float*)&vs_u[0][0];  // ml[q*2+{0,1}] pair1; +128: pair0
  const int qlb = (w & 1) * 32;

  if (p == 1) {
#pragma unroll
    for (int r = 0; r < 16; ++r) {
      const int ql = qlb + (r & 3) + 8 * (r >> 2) + 4 * hi;
      ksf[ql * 64 + lq] = o0[r];
      ksf[ql * 64 + 32 + lq] = o1[r];
    }
    if (l < 32) {
      mlf[(qlb + lq) * 2] = m_;
      mlf[(qlb + lq) * 2 + 1] = l_;
    }
  } else {
    if (l < 32) {
      mlf[128 + (qlb + lq) * 2] = m_;
      mlf[128 + (qlb + lq) * 2 + 1] = l_;
    }
  }
  __syncthreads();

  if (p == 0) {
#pragma unroll
    for (int r = 0; r < 16; ++r) {
      const int ql = qlb + (r & 3) + 8 * (r >> 2) + 4 * hi;
      const float mB = mlf[ql * 2], lB = mlf[ql * 2 + 1];
      const float mA = mlf[128 + ql * 2], lA = mlf[128 + ql * 2 + 1];
      const float mm = fmaxf(mA, mB);
      const float al = exp2f(mA - mm), be = exp2f(mB - mm);
      const float li = 1.0f / (lA * al + lB * be);
      const float fa = al * li, fb = be * li;
      const int qg = blockIdx.y * 64 + ql;
      const size_t base = ((size_t)b * S_ + qg) * D_ + h * DK_;
      ctxb[base + lq] = f2bf(o0[r] * fa + ksf[ql * 64 + lq] * fb);
      ctxb[base + 32 + lq] = f2bf(o1[r] * fa + ksf[ql * 64 + 32 + lq] * fb);
    }
  }
}

// ---------------------------------------------------------------------------
// Kernel 3a: Wo fp32 [K][N] -> WoT bf16 [N][K]
// ---------------------------------------------------------------------------
__global__ __launch_bounds__(256) void wo_transpose(
    const float* __restrict__ Wo, unsigned short* __restrict__ WoT) {
  __shared__ float t[64][65];
  const int k0 = blockIdx.x * 64, n0 = blockIdx.y * 64;
  const int r = threadIdx.x >> 4, c4 = threadIdx.x & 15;
#pragma unroll
  for (int i = 0; i < 4; ++i) {
    float4 v = *(const float4*)&Wo[(size_t)(k0 + r + 16 * i) * D_ + n0 + c4 * 4];
    t[r + 16 * i][c4 * 4 + 0] = v.x;
    t[r + 16 * i][c4 * 4 + 1] = v.y;
    t[r + 16 * i][c4 * 4 + 2] = v.z;
    t[r + 16 * i][c4 * 4 + 3] = v.w;
  }
  __syncthreads();
  const int n = threadIdx.x >> 2, kc = threadIdx.x & 3;
  union {
    unsigned short u[16];
    uint4 v[2];
  } pk;
#pragma unroll
  for (int j = 0; j < 16; ++j) pk.u[j] = f2bf(t[kc * 16 + j][n]);
  unsigned short* op = WoT + (size_t)(n0 + n) * D_ + k0 + kc * 16;
  *(uint4*)op = pk.v[0];
  *(uint4*)(op + 8) = pk.v[1];
}

// ---------------------------------------------------------------------------
// Kernel 3b: out[4096,1024] = ctx_bf16 @ WoT^T + bo, bf16 MFMA, fp32 out.
// ---------------------------------------------------------------------------
__global__ __launch_bounds__(256) void out_gemm_mfma(
    const unsigned short* __restrict__ A,
    const unsigned short* __restrict__ BT,
    const float* __restrict__ bo, float* __restrict__ C) {
  __shared__ __align__(16) unsigned short As[128 * 64];
  __shared__ __align__(16) unsigned short Bs[128 * 64];

  const int tid = threadIdx.x;
  const int w = tid >> 6, l = tid & 63;
  const int ll = l & 15, lg = l >> 4;
  const int wr = w >> 1, wc = w & 1;
  const int m0 = blockIdx.y * 128, n0 = blockIdx.x * 128;

  const int srow = l >> 3;
  const int sslot = (l & 7) ^ srow;
  const int g_off = sslot * 8;

  f32x4 acc[4][4];
#pragma unroll
  for (int mt = 0; mt < 4; ++mt)
#pragma unroll
    for (int nt = 0; nt < 4; ++nt) acc[mt][nt] = (f32x4){0.f, 0.f, 0.f, 0.f};

  for (int k0 = 0; k0 < D_; k0 += 64) {
    __syncthreads();
#pragma unroll
    for (int c = 0; c < 4; ++c) {
      const int row = c * 32 + w * 8 + srow;
      load16_lds(A + (size_t)(m0 + row) * D_ + k0 + g_off,
                 (char*)As + c * 4096 + w * 1024);
      load16_lds(BT + (size_t)(n0 + row) * D_ + k0 + g_off,
                 (char*)Bs + c * 4096 + w * 1024);
    }
    __syncthreads();

#pragma unroll
    for (int half = 0; half < 2; ++half) {
      bf16x8 af[4], bfr[4];
#pragma unroll
      for (int mt = 0; mt < 4; ++mt) {
        const int row = wr * 64 + mt * 16 + ll;
        af[mt] = *(const bf16x8*)((const char*)As + row * 128 +
                                  (((half * 4 + lg) ^ (row & 7)) << 4));
      }
#pragma unroll
      for (int nt = 0; nt < 4; ++nt) {
        const int rowb = wc * 64 + nt * 16 + ll;
        bfr[nt] = *(const bf16x8*)((const char*)Bs + rowb * 128 +
                                   (((half * 4 + lg) ^ (rowb & 7)) << 4));
      }
#pragma unroll
      for (int mt = 0; mt < 4; ++mt)
#pragma unroll
        for (int nt = 0; nt < 4; ++nt)
          acc[mt][nt] = __builtin_amdgcn_mfma_f32_16x16x32_bf16(
              af[mt], bfr[nt], acc[mt][nt], 0, 0, 0);
    }
  }

#pragma unroll
  for (int nt = 0; nt < 4; ++nt) {
    const int col = n0 + wc * 64 + nt * 16 + ll;
    const float bv = bo[col];
#pragma unroll
    for (int mt = 0; mt < 4; ++mt) {
      const int row0 = m0 + wr * 64 + mt * 16 + lg * 4;
#pragma unroll
      for (int r = 0; r < 4; ++r)
        C[(size_t)(row0 + r) * D_ + col] = acc[mt][nt][r] + bv;
    }
  }
}

// ---------------------------------------------------------------------------
extern "C" void kernel_launch(void* const* d_in, const int* in_sizes, int n_in,
                              void* d_out, int out_size, void* d_ws,
                              size_t ws_size, hipStream_t stream) {
  const float* q = (const float*)d_in[0];
  const float* k = (const float*)d_in[1];
  const float* v = (const float*)d_in[2];
  const float* Wq1 = (const float*)d_in[3];
  const float* bq1 = (const float*)d_in[4];
  const float* Wq2 = (const float*)d_in[5];
  const float* bq2 = (const float*)d_in[6];
  const float* Wk1 = (const float*)d_in[7];
  const float* bk1 = (const float*)d_in[8];
  const float* Wk2 = (const float*)d_in[9];
  const float* bk2 = (const float*)d_in[10];
  const float* Wv1 = (const float*)d_in[11];
  const float* bv1 = (const float*)d_in[12];
  const float* Wv2 = (const float*)d_in[13];
  const float* bv2 = (const float*)d_in[14];
  const float* Wo = (const float*)d_in[15];
  const float* bo = (const float*)d_in[16];
  float* out = (float*)d_out;

  const size_t TEN = (size_t)B_ * H_ * S_ * DK_;  // 4,194,304 elements
  char* ws = (char*)d_ws;
  unsigned short* qhb = (unsigned short*)ws;              // bf16 [BH,S,DK]
  unsigned short* khb = (unsigned short*)(ws + TEN * 2);  // bf16 [BH,S,DK]
  unsigned short* vtb = (unsigned short*)(ws + TEN * 4);  // bf16 [BH,DK,S]
  unsigned short* ctxb = (unsigned short*)(ws + TEN * 6); // bf16 [B,S,D]
  unsigned short* wot = (unsigned short*)(ws + TEN * 8);  // bf16 [N,K] = Wo^T

  const float cs = 0.125f * 1.44269504088896340736f;  // 1/sqrt(64) * log2(e)
  quantum_fused<<<dim3(16, 32, 3), 256, 0, stream>>>(
      q, k, v, Wq1, bq1, Wq2, bq2, Wk1, bk1, Wk2, bk2, Wv1, bv1, Wv2, bv2,
      qhb, khb, vtb, cs);
  wo_transpose<<<dim3(16, 16), 256, 0, stream>>>(Wo, wot);

  attn_kernel<<<dim3(32, 32), 256, 0, stream>>>(qhb, khb, vtb, ctxb);

  out_gemm_mfma<<<dim3(8, 32), 256, 0, stream>>>(ctxb, wot, bo, out);
}

// Round 7
// 130.101 us; speedup vs baseline: 1.7055x; 1.7055x over previous
//
#include <hip/hip_runtime.h>

#define B_ 2
#define S_ 2048
#define D_ 1024
#define H_ 16
#define DK_ 64

typedef float f32x4 __attribute__((ext_vector_type(4)));
typedef float f32x16 __attribute__((ext_vector_type(16)));
typedef short bf16x8 __attribute__((ext_vector_type(8)));

static __device__ __forceinline__ unsigned short f2bf(float f) {
  unsigned u = __float_as_uint(f);
  unsigned r = (u + 0x7FFFu + ((u >> 16) & 1u)) >> 16;
  return (unsigned short)r;
}

static __device__ __forceinline__ unsigned cvtpk_bf16(float lo, float hi) {
  unsigned r;
  asm("v_cvt_pk_bf16_f32 %0, %1, %2" : "=v"(r) : "v"(lo), "v"(hi));
  return r;
}

static __device__ __forceinline__ void load16_lds(const void* g, void* lds) {
  __builtin_amdgcn_global_load_lds(
      (const __attribute__((address_space(1))) unsigned int*)g,
      (__attribute__((address_space(3))) unsigned int*)lds, 16, 0, 0);
}

// gather 8 consecutive C-rows of this lane's owned column from crow-scattered
// accumulator regs p[0..7]; returns the 8 bf16 packed (A-frag k-slice).
static __device__ __forceinline__ bf16x8 make_pa8(const float* p, int hi) {
  unsigned x1 = cvtpk_bf16(p[0], p[1]);
  unsigned x2 = cvtpk_bf16(p[2], p[3]);
  unsigned y1 = cvtpk_bf16(p[4], p[5]);
  unsigned y2 = cvtpk_bf16(p[6], p[7]);
  unsigned sx1 = (unsigned)__shfl_xor((int)x1, 32);
  unsigned sx2 = (unsigned)__shfl_xor((int)x2, 32);
  unsigned sy1 = (unsigned)__shfl_xor((int)y1, 32);
  unsigned sy2 = (unsigned)__shfl_xor((int)y2, 32);
  union {
    unsigned u[4];
    bf16x8 v;
  } pa;
  pa.u[0] = hi ? sy1 : x1;
  pa.u[1] = hi ? sy2 : x2;
  pa.u[2] = hi ? y1 : sx1;
  pa.u[3] = hi ? y2 : sx2;
  return pa.v;
}

static __device__ __forceinline__ float tanh_fast(float x) {
  float xc = fminf(fmaxf(x, -9.0f), 9.0f);
  float e = exp2f(xc * 2.88539008177792681472f);  // 2*log2(e)
  return (e - 1.0f) / (e + 1.0f);
}

// ---------------------------------------------------------------------------
// Kernel 1: fused MFMA quantum transform for q, k, v (blockIdx.z selects).
// ---------------------------------------------------------------------------
__global__ __launch_bounds__(256) void quantum_fused(
    const float* __restrict__ xq, const float* __restrict__ xk,
    const float* __restrict__ xv,
    const float* __restrict__ Wq1, const float* __restrict__ bq1,
    const float* __restrict__ Wq2, const float* __restrict__ bq2,
    const float* __restrict__ Wk1, const float* __restrict__ bk1,
    const float* __restrict__ Wk2, const float* __restrict__ bk2,
    const float* __restrict__ Wv1, const float* __restrict__ bv1,
    const float* __restrict__ Wv2, const float* __restrict__ bv2,
    unsigned short* __restrict__ qhb, unsigned short* __restrict__ khb,
    unsigned short* __restrict__ vtb, float qscale) {
  const int tid = threadIdx.x;
  const int w = tid >> 6;
  const int l = tid & 63;
  const int lq = l & 31;
  const int hi = l >> 5;
  const int bh = blockIdx.y;
  const int b = bh >> 4, h = bh & 15;
  const int s0w = blockIdx.x * 128 + w * 32;

  const float* x;
  const float* W1;
  const float* b1;
  const float* W2;
  const float* b2;
  unsigned short* outp;
  float scale = 1.0f;
  int vmode = 0;
  if (blockIdx.z == 0) {
    x = xq; W1 = Wq1; b1 = bq1; W2 = Wq2; b2 = bq2; outp = qhb;
    scale = qscale;
  } else if (blockIdx.z == 1) {
    x = xk; W1 = Wk1; b1 = bk1; W2 = Wk2; b2 = bk2; outp = khb;
  } else {
    x = xv; W1 = Wv1; b1 = bv1; W2 = Wv2; b2 = bv2; outp = vtb;
    vmode = 1;
  }

  bf16x8 w1f[2][4];
#pragma unroll
  for (int ca = 0; ca < 2; ++ca)
#pragma unroll
    for (int kc = 0; kc < 4; ++kc) {
      const float* wp = W1 + (size_t)(kc * 16 + hi * 8) * 64 + ca * 32 + lq;
      union {
        unsigned u[4];
        bf16x8 v;
      } ww;
#pragma unroll
      for (int jj = 0; jj < 4; ++jj)
        ww.u[jj] = cvtpk_bf16(wp[(2 * jj) * 64], wp[(2 * jj + 1) * 64]);
      w1f[ca][kc] = ww.v;
    }

  const float* xrow = x + (((size_t)b * S_ + s0w + lq) * H_ + h) * DK_;
  bf16x8 xf[4];
#pragma unroll
  for (int kc = 0; kc < 4; ++kc) {
    float4 f0 = *(const float4*)(xrow + kc * 16 + hi * 8);
    float4 f1 = *(const float4*)(xrow + kc * 16 + hi * 8 + 4);
    union {
      unsigned u[4];
      bf16x8 v;
    } xx;
    xx.u[0] = cvtpk_bf16(f0.x, f0.y);
    xx.u[1] = cvtpk_bf16(f0.z, f0.w);
    xx.u[2] = cvtpk_bf16(f1.x, f1.y);
    xx.u[3] = cvtpk_bf16(f1.z, f1.w);
    xf[kc] = xx.v;
  }

  f32x16 acc1[2];
#pragma unroll
  for (int ca = 0; ca < 2; ++ca)
#pragma unroll
    for (int r = 0; r < 16; ++r)
      acc1[ca][r] = b1[ca * 32 + (r & 3) + 8 * (r >> 2) + 4 * hi];
#pragma unroll
  for (int kc = 0; kc < 4; ++kc) {
    acc1[0] = __builtin_amdgcn_mfma_f32_32x32x16_bf16(w1f[0][kc], xf[kc], acc1[0], 0, 0, 0);
    acc1[1] = __builtin_amdgcn_mfma_f32_32x32x16_bf16(w1f[1][kc], xf[kc], acc1[1], 0, 0, 0);
  }

  float t0[16], t1[16];
#pragma unroll
  for (int r = 0; r < 16; ++r) {
    t0[r] = tanh_fast(acc1[0][r]);
    t1[r] = tanh_fast(acc1[1][r]);
  }

  bf16x8 af[4];
  af[0] = make_pa8(&t0[0], hi);
  af[1] = make_pa8(&t0[8], hi);
  af[2] = make_pa8(&t1[0], hi);
  af[3] = make_pa8(&t1[8], hi);

  bf16x8 w2f[2][4];
#pragma unroll
  for (int nb = 0; nb < 2; ++nb)
#pragma unroll
    for (int kc = 0; kc < 4; ++kc) {
      const float* wp = W2 + (size_t)(kc * 16 + hi * 8) * 64 + nb * 32 + lq;
      union {
        unsigned u[4];
        bf16x8 v;
      } ww;
#pragma unroll
      for (int jj = 0; jj < 4; ++jj)
        ww.u[jj] = cvtpk_bf16(wp[(2 * jj) * 64], wp[(2 * jj + 1) * 64]);
      w2f[nb][kc] = ww.v;
    }

  f32x16 acc2[2];
#pragma unroll
  for (int nb = 0; nb < 2; ++nb)
#pragma unroll
    for (int r = 0; r < 16; ++r)
      acc2[nb][r] = b2[nb * 32 + (r & 3) + 8 * (r >> 2) + 4 * hi];
#pragma unroll
  for (int kc = 0; kc < 4; ++kc) {
    acc2[0] = __builtin_amdgcn_mfma_f32_32x32x16_bf16(af[kc], w2f[0][kc], acc2[0], 0, 0, 0);
    acc2[1] = __builtin_amdgcn_mfma_f32_32x32x16_bf16(af[kc], w2f[1][kc], acc2[1], 0, 0, 0);
  }

  if (!vmode) {
#pragma unroll
    for (int nb = 0; nb < 2; ++nb)
#pragma unroll
      for (int r = 0; r < 16; ++r) {
        const int s = s0w + (r & 3) + 8 * (r >> 2) + 4 * hi;
        outp[((size_t)bh * S_ + s) * DK_ + nb * 32 + lq] =
            f2bf(acc2[nb][r] * scale);
      }
  } else {
#pragma unroll
    for (int nb = 0; nb < 2; ++nb) {
      float yv[16];
#pragma unroll
      for (int r = 0; r < 16; ++r) yv[r] = acc2[nb][r];
      const size_t rowb = ((size_t)bh * DK_ + nb * 32 + lq) * S_;
      *(bf16x8*)(outp + rowb + s0w + hi * 8) = make_pa8(&yv[0], hi);
      *(bf16x8*)(outp + rowb + s0w + 16 + hi * 8) = make_pa8(&yv[8], hi);
    }
  }
}

// ---------------------------------------------------------------------------
// Kernel 2: MFMA flash attention, swapped-QK^T 32x32x16, in-block K-split x2.
// 4 waves = 2 pairs; pair p handles keys [p*1024, p*1024+1024) of a 64-row
// q-block; wave within pair owns 32 q-rows. Staging: global->LDS directly
// between barriers (NO register prefetch -- r6's spill lesson). Final merge
// through LDS. grid (32 bh, 32 q-blocks of 64), block 256.
// ---------------------------------------------------------------------------
__global__ __launch_bounds__(256, 3) void attn_kernel(
    const unsigned short* __restrict__ qhb,
    const unsigned short* __restrict__ khb,
    const unsigned short* __restrict__ vtb,
    unsigned short* __restrict__ ctxb) {
  __shared__ __align__(16) unsigned short ks_u[2][64 * 64];  // per-pair K tile
  __shared__ __align__(16) unsigned short vs_u[2][64 * 64];  // per-pair V^T

  const int tid = threadIdx.x;
  const int w = tid >> 6;
  const int p = w >> 1;   // K-half
  const int l = tid & 63;
  const int lq = l & 31;
  const int hi = l >> 5;
  const int bh = blockIdx.x;
  const int b = bh >> 4, h = bh & 15;
  const int q0 = blockIdx.y * 64 + (w & 1) * 32;

  // Q fragments for the whole kernel (pre-scaled by 1/8*log2e)
  const unsigned short* qp = qhb + ((size_t)bh * S_ + q0 + lq) * DK_ + hi * 8;
  bf16x8 qf[4];
#pragma unroll
  for (int kc = 0; kc < 4; ++kc) qf[kc] = *(const bf16x8*)(qp + kc * 16);

  f32x16 o0 = {}, o1 = {};
  float m_ = -1e30f, l_ = 0.f;

  // staging roles: 128 threads per pair move the pair's 16KB tile set
  const int kk = (tid & 127) >> 1;  // row 0..63
  const int ch2 = tid & 1;          // 64B-half of the row
  const unsigned short* kgbase = khb + (size_t)bh * S_ * DK_;
  const unsigned short* vgbase = vtb + (size_t)bh * DK_ * S_;
  char* ksP = (char*)&ks_u[p][0];
  char* vsP = (char*)&vs_u[p][0];

  for (int t = 0; t < 16; ++t) {
    __syncthreads();  // previous tile's LDS reads complete
    {
      const int tb = p * 1024 + t * 64;
      const uint4* gk = (const uint4*)(kgbase + (size_t)(tb + kk) * DK_ + ch2 * 32);
      const uint4* gv = (const uint4*)(vgbase + (size_t)kk * S_ + tb + ch2 * 32);
      char* kd = ksP + kk * 128;
      char* vd = vsP + kk * 128;
#pragma unroll
      for (int j = 0; j < 4; ++j) {
        uint4 a = gk[j];
        uint4 bb = gv[j];
        *(uint4*)(kd + (((ch2 * 4 + j) ^ (kk & 7)) << 4)) = a;
        *(uint4*)(vd + (((ch2 * 4 + j) ^ (kk & 7)) << 4)) = bb;
      }
    }
    __syncthreads();

    // ---- QK^T: S^T[k][q=lq] ----
    f32x16 s0 = {}, s1 = {};
#pragma unroll
    for (int kc = 0; kc < 4; ++kc) {
      const int slot = kc * 2 + hi;
      bf16x8 k0 = *(const bf16x8*)(ksP + lq * 128 + ((slot ^ (lq & 7)) << 4));
      bf16x8 k1 = *(const bf16x8*)(ksP + (32 + lq) * 128 + ((slot ^ (lq & 7)) << 4));
      s0 = __builtin_amdgcn_mfma_f32_32x32x16_bf16(k0, qf[kc], s0, 0, 0, 0);
      s1 = __builtin_amdgcn_mfma_f32_32x32x16_bf16(k1, qf[kc], s1, 0, 0, 0);
    }

    // ---- lane-local online softmax with defer-max (THR=8) ----
    float pmax = s0[0];
#pragma unroll
    for (int i = 1; i < 16; ++i) pmax = fmaxf(pmax, s0[i]);
#pragma unroll
    for (int i = 0; i < 16; ++i) pmax = fmaxf(pmax, s1[i]);
    pmax = fmaxf(pmax, __shfl_xor(pmax, 32));

    if (!__all(pmax <= m_ + 8.0f)) {
      const float mnew = fmaxf(m_, pmax);
      const float scl = exp2f(m_ - mnew);
      m_ = mnew;
      l_ *= scl;
#pragma unroll
      for (int r = 0; r < 16; ++r) {
        const float sr = __shfl(scl, ((r & 3) + 8 * (r >> 2)) + 4 * hi);
        o0[r] *= sr;
        o1[r] *= sr;
      }
    }

    // exp2 in place (P values)
#pragma unroll
    for (int i = 0; i < 16; ++i) s0[i] = exp2f(s0[i] - m_);
#pragma unroll
    for (int i = 0; i < 16; ++i) s1[i] = exp2f(s1[i] - m_);
    {
      float t0a = 0.f, t1a = 0.f, t2a = 0.f, t3a = 0.f;
#pragma unroll
      for (int i = 0; i < 16; i += 4) {
        t0a += s0[i] + s1[i];
        t1a += s0[i + 1] + s1[i + 1];
        t2a += s0[i + 2] + s1[i + 2];
        t3a += s0[i + 3] + s1[i + 3];
      }
      float ps = (t0a + t1a) + (t2a + t3a);
      ps += __shfl_xor(ps, 32);
      l_ += ps;
    }

    // ---- P -> A-frags + PV ----
    float pv[8];
    union {
      unsigned u[4];
      bf16x8 v;
    } pa;

#define PV_STEP(SARR, CC, CIDX)                                               \
  {                                                                           \
    _Pragma("unroll") for (int j = 0; j < 8; ++j) pv[j] = SARR[(CC)*8 + j];   \
    pa.v = make_pa8(pv, hi);                                                  \
    const int slot = (CIDX)*2 + hi;                                           \
    bf16x8 v0 = *(const bf16x8*)(vsP + lq * 128 + ((slot ^ (lq & 7)) << 4));  \
    bf16x8 v1 = *(const bf16x8*)(vsP + (32 + lq) * 128 + ((slot ^ (lq & 7)) << 4)); \
    o0 = __builtin_amdgcn_mfma_f32_32x32x16_bf16(pa.v, v0, o0, 0, 0, 0);      \
    o1 = __builtin_amdgcn_mfma_f32_32x32x16_bf16(pa.v, v1, o1, 0, 0, 0);      \
  }

    PV_STEP(s0, 0, 0)
    PV_STEP(s0, 1, 1)
    PV_STEP(s1, 0, 2)
    PV_STEP(s1, 1, 3)
#undef PV_STEP
  }

  // ---- cross-pair merge through LDS ----
  __syncthreads();  // all compute reads of LDS done before repurposing
  float* ksf = (float*)&ks_u[0][0];  // [64][64] fp32: pair-1 O partial
  float* mlf = (float*)&vs_u[0][0];  // ml[q*2+{0,1}] pair1; +128: pair0
  const int qlb = (w & 1) * 32;

  if (p == 1) {
#pragma unroll
    for (int r = 0; r < 16; ++r) {
      const int ql = qlb + (r & 3) + 8 * (r >> 2) + 4 * hi;
      ksf[ql * 64 + lq] = o0[r];
      ksf[ql * 64 + 32 + lq] = o1[r];
    }
    if (l < 32) {
      mlf[(qlb + lq) * 2] = m_;
      mlf[(qlb + lq) * 2 + 1] = l_;
    }
  } else {
    if (l < 32) {
      mlf[128 + (qlb + lq) * 2] = m_;
      mlf[128 + (qlb + lq) * 2 + 1] = l_;
    }
  }
  __syncthreads();

  if (p == 0) {
#pragma unroll
    for (int r = 0; r < 16; ++r) {
      const int ql = qlb + (r & 3) + 8 * (r >> 2) + 4 * hi;
      const float mB = mlf[ql * 2], lB = mlf[ql * 2 + 1];
      const float mA = mlf[128 + ql * 2], lA = mlf[128 + ql * 2 + 1];
      const float mm = fmaxf(mA, mB);
      const float al = exp2f(mA - mm), be = exp2f(mB - mm);
      const float li = 1.0f / (lA * al + lB * be);
      const float fa = al * li, fb = be * li;
      const int qg = blockIdx.y * 64 + ql;
      const size_t base = ((size_t)b * S_ + qg) * D_ + h * DK_;
      ctxb[base + lq] = f2bf(o0[r] * fa + ksf[ql * 64 + lq] * fb);
      ctxb[base + 32 + lq] = f2bf(o1[r] * fa + ksf[ql * 64 + 32 + lq] * fb);
    }
  }
}

// ---------------------------------------------------------------------------
// Kernel 3a: Wo fp32 [K][N] -> WoT bf16 [N][K]
// ---------------------------------------------------------------------------
__global__ __launch_bounds__(256) void wo_transpose(
    const float* __restrict__ Wo, unsigned short* __restrict__ WoT) {
  __shared__ float t[64][65];
  const int k0 = blockIdx.x * 64, n0 = blockIdx.y * 64;
  const int r = threadIdx.x >> 4, c4 = threadIdx.x & 15;
#pragma unroll
  for (int i = 0; i < 4; ++i) {
    float4 v = *(const float4*)&Wo[(size_t)(k0 + r + 16 * i) * D_ + n0 + c4 * 4];
    t[r + 16 * i][c4 * 4 + 0] = v.x;
    t[r + 16 * i][c4 * 4 + 1] = v.y;
    t[r + 16 * i][c4 * 4 + 2] = v.z;
    t[r + 16 * i][c4 * 4 + 3] = v.w;
  }
  __syncthreads();
  const int n = threadIdx.x >> 2, kc = threadIdx.x & 3;
  union {
    unsigned short u[16];
    uint4 v[2];
  } pk;
#pragma unroll
  for (int j = 0; j < 16; ++j) pk.u[j] = f2bf(t[kc * 16 + j][n]);
  unsigned short* op = WoT + (size_t)(n0 + n) * D_ + k0 + kc * 16;
  *(uint4*)op = pk.v[0];
  *(uint4*)(op + 8) = pk.v[1];
}

// ---------------------------------------------------------------------------
// Kernel 3b: out[4096,1024] = ctx_bf16 @ WoT^T + bo, bf16 MFMA, fp32 out.
// ---------------------------------------------------------------------------
__global__ __launch_bounds__(256) void out_gemm_mfma(
    const unsigned short* __restrict__ A,
    const unsigned short* __restrict__ BT,
    const float* __restrict__ bo, float* __restrict__ C) {
  __shared__ __align__(16) unsigned short As[128 * 64];
  __shared__ __align__(16) unsigned short Bs[128 * 64];

  const int tid = threadIdx.x;
  const int w = tid >> 6, l = tid & 63;
  const int ll = l & 15, lg = l >> 4;
  const int wr = w >> 1, wc = w & 1;
  const int m0 = blockIdx.y * 128, n0 = blockIdx.x * 128;

  const int srow = l >> 3;
  const int sslot = (l & 7) ^ srow;
  const int g_off = sslot * 8;

  f32x4 acc[4][4];
#pragma unroll
  for (int mt = 0; mt < 4; ++mt)
#pragma unroll
    for (int nt = 0; nt < 4; ++nt) acc[mt][nt] = (f32x4){0.f, 0.f, 0.f, 0.f};

  for (int k0 = 0; k0 < D_; k0 += 64) {
    __syncthreads();
#pragma unroll
    for (int c = 0; c < 4; ++c) {
      const int row = c * 32 + w * 8 + srow;
      load16_lds(A + (size_t)(m0 + row) * D_ + k0 + g_off,
                 (char*)As + c * 4096 + w * 1024);
      load16_lds(BT + (size_t)(n0 + row) * D_ + k0 + g_off,
                 (char*)Bs + c * 4096 + w * 1024);
    }
    __syncthreads();

#pragma unroll
    for (int half = 0; half < 2; ++half) {
      bf16x8 af[4], bfr[4];
#pragma unroll
      for (int mt = 0; mt < 4; ++mt) {
        const int row = wr * 64 + mt * 16 + ll;
        af[mt] = *(const bf16x8*)((const char*)As + row * 128 +
                                  (((half * 4 + lg) ^ (row & 7)) << 4));
      }
#pragma unroll
      for (int nt = 0; nt < 4; ++nt) {
        const int rowb = wc * 64 + nt * 16 + ll;
        bfr[nt] = *(const bf16x8*)((const char*)Bs + rowb * 128 +
                                   (((half * 4 + lg) ^ (rowb & 7)) << 4));
      }
#pragma unroll
      for (int mt = 0; mt < 4; ++mt)
#pragma unroll
        for (int nt = 0; nt < 4; ++nt)
          acc[mt][nt] = __builtin_amdgcn_mfma_f32_16x16x32_bf16(
              af[mt], bfr[nt], acc[mt][nt], 0, 0, 0);
    }
  }

#pragma unroll
  for (int nt = 0; nt < 4; ++nt) {
    const int col = n0 + wc * 64 + nt * 16 + ll;
    const float bv = bo[col];
#pragma unroll
    for (int mt = 0; mt < 4; ++mt) {
      const int row0 = m0 + wr * 64 + mt * 16 + lg * 4;
#pragma unroll
      for (int r = 0; r < 4; ++r)
        C[(size_t)(row0 + r) * D_ + col] = acc[mt][nt][r] + bv;
    }
  }
}

// ---------------------------------------------------------------------------
extern "C" void kernel_launch(void* const* d_in, const int* in_sizes, int n_in,
                              void* d_out, int out_size, void* d_ws,
                              size_t ws_size, hipStream_t stream) {
  const float* q = (const float*)d_in[0];
  const float* k = (const float*)d_in[1];
  const float* v = (const float*)d_in[2];
  const float* Wq1 = (const float*)d_in[3];
  const float* bq1 = (const float*)d_in[4];
  const float* Wq2 = (const float*)d_in[5];
  const float* bq2 = (const float*)d_in[6];
  const float* Wk1 = (const float*)d_in[7];
  const float* bk1 = (const float*)d_in[8];
  const float* Wk2 = (const float*)d_in[9];
  const float* bk2 = (const float*)d_in[10];
  const float* Wv1 = (const float*)d_in[11];
  const float* bv1 = (const float*)d_in[12];
  const float* Wv2 = (const float*)d_in[13];
  const float* bv2 = (const float*)d_in[14];
  const float* Wo = (const float*)d_in[15];
  const float* bo = (const float*)d_in[16];
  float* out = (float*)d_out;

  const size_t TEN = (size_t)B_ * H_ * S_ * DK_;  // 4,194,304 elements
  char* ws = (char*)d_ws;
  unsigned short* qhb = (unsigned short*)ws;              // bf16 [BH,S,DK]
  unsigned short* khb = (unsigned short*)(ws + TEN * 2);  // bf16 [BH,S,DK]
  unsigned short* vtb = (unsigned short*)(ws + TEN * 4);  // bf16 [BH,DK,S]
  unsigned short* ctxb = (unsigned short*)(ws + TEN * 6); // bf16 [B,S,D]
  unsigned short* wot = (unsigned short*)(ws + TEN * 8);  // bf16 [N,K] = Wo^T

  const float cs = 0.125f * 1.44269504088896340736f;  // 1/sqrt(64) * log2(e)
  quantum_fused<<<dim3(16, 32, 3), 256, 0, stream>>>(
      q, k, v, Wq1, bq1, Wq2, bq2, Wk1, bk1, Wk2, bk2, Wv1, bv1, Wv2, bv2,
      qhb, khb, vtb, cs);
  wo_transpose<<<dim3(16, 16), 256, 0, stream>>>(Wo, wot);

  attn_kernel<<<dim3(32, 32), 256, 0, stream>>>(qhb, khb, vtb, ctxb);

  out_gemm_mfma<<<dim3(8, 32), 256, 0, stream>>>(ctxb, wot, bo, out);
}

// Round 8
// 122.022 us; speedup vs baseline: 1.8184x; 1.0662x over previous
//
#include <hip/hip_runtime.h>

#define B_ 2
#define S_ 2048
#define D_ 1024
#define H_ 16
#define DK_ 64

typedef float f32x4 __attribute__((ext_vector_type(4)));
typedef float f32x16 __attribute__((ext_vector_type(16)));
typedef short bf16x8 __attribute__((ext_vector_type(8)));

static __device__ __forceinline__ unsigned short f2bf(float f) {
  unsigned u = __float_as_uint(f);
  unsigned r = (u + 0x7FFFu + ((u >> 16) & 1u)) >> 16;
  return (unsigned short)r;
}

static __device__ __forceinline__ unsigned cvtpk_bf16(float lo, float hi) {
  unsigned r;
  asm("v_cvt_pk_bf16_f32 %0, %1, %2" : "=v"(r) : "v"(lo), "v"(hi));
  return r;
}

static __device__ __forceinline__ void load16_lds(const void* g, void* lds) {
  __builtin_amdgcn_global_load_lds(
      (const __attribute__((address_space(1))) unsigned int*)g,
      (__attribute__((address_space(3))) unsigned int*)lds, 16, 0, 0);
}

// gather 8 consecutive C-rows of this lane's owned column from crow-scattered
// accumulator regs p[0..7]; returns the 8 bf16 packed (A-frag k-slice).
static __device__ __forceinline__ bf16x8 make_pa8(const float* p, int hi) {
  unsigned x1 = cvtpk_bf16(p[0], p[1]);
  unsigned x2 = cvtpk_bf16(p[2], p[3]);
  unsigned y1 = cvtpk_bf16(p[4], p[5]);
  unsigned y2 = cvtpk_bf16(p[6], p[7]);
  unsigned sx1 = (unsigned)__shfl_xor((int)x1, 32);
  unsigned sx2 = (unsigned)__shfl_xor((int)x2, 32);
  unsigned sy1 = (unsigned)__shfl_xor((int)y1, 32);
  unsigned sy2 = (unsigned)__shfl_xor((int)y2, 32);
  union {
    unsigned u[4];
    bf16x8 v;
  } pa;
  pa.u[0] = hi ? sy1 : x1;
  pa.u[1] = hi ? sy2 : x2;
  pa.u[2] = hi ? y1 : sx1;
  pa.u[3] = hi ? y2 : sx2;
  return pa.v;
}

static __device__ __forceinline__ float tanh_fast(float x) {
  float xc = fminf(fmaxf(x, -9.0f), 9.0f);
  float e = exp2f(xc * 2.88539008177792681472f);  // 2*log2(e)
  return (e - 1.0f) / (e + 1.0f);
}

// ---------------------------------------------------------------------------
// Kernel 1: fused MFMA quantum transform for q, k, v (blockIdx.z selects).
// ---------------------------------------------------------------------------
__global__ __launch_bounds__(256) void quantum_fused(
    const float* __restrict__ xq, const float* __restrict__ xk,
    const float* __restrict__ xv,
    const float* __restrict__ Wq1, const float* __restrict__ bq1,
    const float* __restrict__ Wq2, const float* __restrict__ bq2,
    const float* __restrict__ Wk1, const float* __restrict__ bk1,
    const float* __restrict__ Wk2, const float* __restrict__ bk2,
    const float* __restrict__ Wv1, const float* __restrict__ bv1,
    const float* __restrict__ Wv2, const float* __restrict__ bv2,
    unsigned short* __restrict__ qhb, unsigned short* __restrict__ khb,
    unsigned short* __restrict__ vtb, float qscale) {
  const int tid = threadIdx.x;
  const int w = tid >> 6;
  const int l = tid & 63;
  const int lq = l & 31;
  const int hi = l >> 5;
  const int bh = blockIdx.y;
  const int b = bh >> 4, h = bh & 15;
  const int s0w = blockIdx.x * 128 + w * 32;

  const float* x;
  const float* W1;
  const float* b1;
  const float* W2;
  const float* b2;
  unsigned short* outp;
  float scale = 1.0f;
  int vmode = 0;
  if (blockIdx.z == 0) {
    x = xq; W1 = Wq1; b1 = bq1; W2 = Wq2; b2 = bq2; outp = qhb;
    scale = qscale;
  } else if (blockIdx.z == 1) {
    x = xk; W1 = Wk1; b1 = bk1; W2 = Wk2; b2 = bk2; outp = khb;
  } else {
    x = xv; W1 = Wv1; b1 = bv1; W2 = Wv2; b2 = bv2; outp = vtb;
    vmode = 1;
  }

  bf16x8 w1f[2][4];
#pragma unroll
  for (int ca = 0; ca < 2; ++ca)
#pragma unroll
    for (int kc = 0; kc < 4; ++kc) {
      const float* wp = W1 + (size_t)(kc * 16 + hi * 8) * 64 + ca * 32 + lq;
      union {
        unsigned u[4];
        bf16x8 v;
      } ww;
#pragma unroll
      for (int jj = 0; jj < 4; ++jj)
        ww.u[jj] = cvtpk_bf16(wp[(2 * jj) * 64], wp[(2 * jj + 1) * 64]);
      w1f[ca][kc] = ww.v;
    }

  const float* xrow = x + (((size_t)b * S_ + s0w + lq) * H_ + h) * DK_;
  bf16x8 xf[4];
#pragma unroll
  for (int kc = 0; kc < 4; ++kc) {
    float4 f0 = *(const float4*)(xrow + kc * 16 + hi * 8);
    float4 f1 = *(const float4*)(xrow + kc * 16 + hi * 8 + 4);
    union {
      unsigned u[4];
      bf16x8 v;
    } xx;
    xx.u[0] = cvtpk_bf16(f0.x, f0.y);
    xx.u[1] = cvtpk_bf16(f0.z, f0.w);
    xx.u[2] = cvtpk_bf16(f1.x, f1.y);
    xx.u[3] = cvtpk_bf16(f1.z, f1.w);
    xf[kc] = xx.v;
  }

  f32x16 acc1[2];
#pragma unroll
  for (int ca = 0; ca < 2; ++ca)
#pragma unroll
    for (int r = 0; r < 16; ++r)
      acc1[ca][r] = b1[ca * 32 + (r & 3) + 8 * (r >> 2) + 4 * hi];
#pragma unroll
  for (int kc = 0; kc < 4; ++kc) {
    acc1[0] = __builtin_amdgcn_mfma_f32_32x32x16_bf16(w1f[0][kc], xf[kc], acc1[0], 0, 0, 0);
    acc1[1] = __builtin_amdgcn_mfma_f32_32x32x16_bf16(w1f[1][kc], xf[kc], acc1[1], 0, 0, 0);
  }

  float t0[16], t1[16];
#pragma unroll
  for (int r = 0; r < 16; ++r) {
    t0[r] = tanh_fast(acc1[0][r]);
    t1[r] = tanh_fast(acc1[1][r]);
  }

  bf16x8 af[4];
  af[0] = make_pa8(&t0[0], hi);
  af[1] = make_pa8(&t0[8], hi);
  af[2] = make_pa8(&t1[0], hi);
  af[3] = make_pa8(&t1[8], hi);

  bf16x8 w2f[2][4];
#pragma unroll
  for (int nb = 0; nb < 2; ++nb)
#pragma unroll
    for (int kc = 0; kc < 4; ++kc) {
      const float* wp = W2 + (size_t)(kc * 16 + hi * 8) * 64 + nb * 32 + lq;
      union {
        unsigned u[4];
        bf16x8 v;
      } ww;
#pragma unroll
      for (int jj = 0; jj < 4; ++jj)
        ww.u[jj] = cvtpk_bf16(wp[(2 * jj) * 64], wp[(2 * jj + 1) * 64]);
      w2f[nb][kc] = ww.v;
    }

  f32x16 acc2[2];
#pragma unroll
  for (int nb = 0; nb < 2; ++nb)
#pragma unroll
    for (int r = 0; r < 16; ++r)
      acc2[nb][r] = b2[nb * 32 + (r & 3) + 8 * (r >> 2) + 4 * hi];
#pragma unroll
  for (int kc = 0; kc < 4; ++kc) {
    acc2[0] = __builtin_amdgcn_mfma_f32_32x32x16_bf16(af[kc], w2f[0][kc], acc2[0], 0, 0, 0);
    acc2[1] = __builtin_amdgcn_mfma_f32_32x32x16_bf16(af[kc], w2f[1][kc], acc2[1], 0, 0, 0);
  }

  if (!vmode) {
#pragma unroll
    for (int nb = 0; nb < 2; ++nb)
#pragma unroll
      for (int r = 0; r < 16; ++r) {
        const int s = s0w + (r & 3) + 8 * (r >> 2) + 4 * hi;
        outp[((size_t)bh * S_ + s) * DK_ + nb * 32 + lq] =
            f2bf(acc2[nb][r] * scale);
      }
  } else {
#pragma unroll
    for (int nb = 0; nb < 2; ++nb) {
      float yv[16];
#pragma unroll
      for (int r = 0; r < 16; ++r) yv[r] = acc2[nb][r];
      const size_t rowb = ((size_t)bh * DK_ + nb * 32 + lq) * S_;
      *(bf16x8*)(outp + rowb + s0w + hi * 8) = make_pa8(&yv[0], hi);
      *(bf16x8*)(outp + rowb + s0w + 16 + hi * 8) = make_pa8(&yv[8], hi);
    }
  }
}

// ---------------------------------------------------------------------------
// Kernel 2: MFMA flash attention, swapped-QK^T 32x32x16.
// 128-row q-block, 4 waves share one K-pass. Double-buffered K/V staging via
// global_load_lds with PRE-SWIZZLED global source (linear LDS dest, swizzled
// read) -- 2-phase pipeline: issue tile t+1, compute tile t, barrier drains.
// grid (32 bh, 16 q-blocks of 128), block 256.
// ---------------------------------------------------------------------------
__global__ __launch_bounds__(256) void attn_kernel(
    const unsigned short* __restrict__ qhb,
    const unsigned short* __restrict__ khb,
    const unsigned short* __restrict__ vtb,
    unsigned short* __restrict__ ctxb) {
  __shared__ __align__(16) unsigned short ks_u[2][64 * 64];  // dbuf K tiles
  __shared__ __align__(16) unsigned short vs_u[2][64 * 64];  // dbuf V^T tiles

  const int tid = threadIdx.x;
  const int w = tid >> 6;
  const int l = tid & 63;
  const int lq = l & 31;
  const int hi = l >> 5;
  const int bh = blockIdx.x;
  const int b = bh >> 4, h = bh & 15;
  const int q0 = blockIdx.y * 128 + w * 32;

  // Q fragments for the whole kernel (pre-scaled by 1/8*log2e)
  const unsigned short* qp = qhb + ((size_t)bh * S_ + q0 + lq) * DK_ + hi * 8;
  bf16x8 qf[4];
#pragma unroll
  for (int kc = 0; kc < 4; ++kc) qf[kc] = *(const bf16x8*)(qp + kc * 16);

  f32x16 o0 = {}, o1 = {};
  float m_ = -1e30f, l_ = 0.f;

  const unsigned short* kgbase = khb + (size_t)bh * S_ * DK_;
  const unsigned short* vgbase = vtb + (size_t)bh * DK_ * S_;
  // staging: wave w moves LDS rows [w*16, w*16+16) of each tile.
  // LDS dest is linear (wave base + lane*16); global source pre-swizzled so
  // that row kk slot j holds global slot j^(kk&7) (read side XORs it back).
  const int r0 = w * 16 + (l >> 3);
  const int sl8 = ((l & 7) ^ (l >> 3)) * 8;  // elem offset within row

#define STAGE(BUF, TT)                                                        \
  {                                                                           \
    const int tb = (TT)*64;                                                   \
    char* kb = (char*)ks_u[BUF] + w * 2048;                                   \
    char* vb = (char*)vs_u[BUF] + w * 2048;                                   \
    load16_lds(kgbase + (size_t)(tb + r0) * DK_ + sl8, kb);                   \
    load16_lds(kgbase + (size_t)(tb + r0 + 8) * DK_ + sl8, kb + 1024);        \
    load16_lds(vgbase + (size_t)r0 * S_ + tb + sl8, vb);                      \
    load16_lds(vgbase + (size_t)(r0 + 8) * S_ + tb + sl8, vb + 1024);         \
  }

  STAGE(0, 0)
  __syncthreads();  // drain prologue staging

  for (int t = 0; t < 32; ++t) {
    const char* ksP = (const char*)ks_u[t & 1];
    const char* vsP = (const char*)vs_u[t & 1];
    if (t < 31) STAGE((t + 1) & 1, t + 1)  // async: drains at end barrier

    // ---- QK^T: S^T[k][q=lq] ----
    f32x16 s0 = {}, s1 = {};
#pragma unroll
    for (int kc = 0; kc < 4; ++kc) {
      const int slot = kc * 2 + hi;
      bf16x8 k0 = *(const bf16x8*)(ksP + lq * 128 + ((slot ^ (lq & 7)) << 4));
      bf16x8 k1 = *(const bf16x8*)(ksP + (32 + lq) * 128 + ((slot ^ (lq & 7)) << 4));
      s0 = __builtin_amdgcn_mfma_f32_32x32x16_bf16(k0, qf[kc], s0, 0, 0, 0);
      s1 = __builtin_amdgcn_mfma_f32_32x32x16_bf16(k1, qf[kc], s1, 0, 0, 0);
    }

    // ---- lane-local online softmax with defer-max (THR=8) ----
    float pmax = fmaxf(fmaxf(s0[0], s0[1]), fmaxf(s0[2], s0[3]));
#pragma unroll
    for (int i = 4; i < 16; i += 4)
      pmax = fmaxf(pmax, fmaxf(fmaxf(s0[i], s0[i + 1]), fmaxf(s0[i + 2], s0[i + 3])));
#pragma unroll
    for (int i = 0; i < 16; i += 4)
      pmax = fmaxf(pmax, fmaxf(fmaxf(s1[i], s1[i + 1]), fmaxf(s1[i + 2], s1[i + 3])));
    pmax = fmaxf(pmax, __shfl_xor(pmax, 32));

    if (!__all(pmax <= m_ + 8.0f)) {
      const float mnew = fmaxf(m_, pmax);
      const float scl = exp2f(m_ - mnew);
      m_ = mnew;
      l_ *= scl;
#pragma unroll
      for (int r = 0; r < 16; ++r) {
        const float sr = __shfl(scl, ((r & 3) + 8 * (r >> 2)) + 4 * hi);
        o0[r] *= sr;
        o1[r] *= sr;
      }
    }

    // exp2 in place (P values)
#pragma unroll
    for (int i = 0; i < 16; ++i) s0[i] = exp2f(s0[i] - m_);
#pragma unroll
    for (int i = 0; i < 16; ++i) s1[i] = exp2f(s1[i] - m_);
    {
      float t0a = 0.f, t1a = 0.f, t2a = 0.f, t3a = 0.f;
#pragma unroll
      for (int i = 0; i < 16; i += 4) {
        t0a += s0[i] + s1[i];
        t1a += s0[i + 1] + s1[i + 1];
        t2a += s0[i + 2] + s1[i + 2];
        t3a += s0[i + 3] + s1[i + 3];
      }
      float ps = (t0a + t1a) + (t2a + t3a);
      ps += __shfl_xor(ps, 32);
      l_ += ps;
    }

    // ---- P -> A-frags + PV ----
    float pv[8];
    union {
      unsigned u[4];
      bf16x8 v;
    } pa;

#define PV_STEP(SARR, CC, CIDX)                                               \
  {                                                                           \
    _Pragma("unroll") for (int j = 0; j < 8; ++j) pv[j] = SARR[(CC)*8 + j];   \
    pa.v = make_pa8(pv, hi);                                                  \
    const int slot = (CIDX)*2 + hi;                                           \
    bf16x8 v0 = *(const bf16x8*)(vsP + lq * 128 + ((slot ^ (lq & 7)) << 4));  \
    bf16x8 v1 = *(const bf16x8*)(vsP + (32 + lq) * 128 + ((slot ^ (lq & 7)) << 4)); \
    o0 = __builtin_amdgcn_mfma_f32_32x32x16_bf16(pa.v, v0, o0, 0, 0, 0);      \
    o1 = __builtin_amdgcn_mfma_f32_32x32x16_bf16(pa.v, v1, o1, 0, 0, 0);      \
  }

    PV_STEP(s0, 0, 0)
    PV_STEP(s0, 1, 1)
    PV_STEP(s1, 0, 2)
    PV_STEP(s1, 1, 3)
#undef PV_STEP

    __syncthreads();  // readers done + staging drained -> next tile ready
  }
#undef STAGE

  // ---- epilogue: O[q][d] / l_[q], bf16 store ----
  const float linv = 1.0f / l_;
#pragma unroll
  for (int r = 0; r < 16; ++r) {
    const int crow = ((r & 3) + 8 * (r >> 2)) + 4 * hi;
    const float lr = __shfl(linv, crow);
    const int qg = q0 + crow;
    const size_t base = ((size_t)b * S_ + qg) * D_ + h * DK_;
    ctxb[base + lq] = f2bf(o0[r] * lr);
    ctxb[base + 32 + lq] = f2bf(o1[r] * lr);
  }
}

// ---------------------------------------------------------------------------
// Kernel 3a: Wo fp32 [K][N] -> WoT bf16 [N][K]
// ---------------------------------------------------------------------------
__global__ __launch_bounds__(256) void wo_transpose(
    const float* __restrict__ Wo, unsigned short* __restrict__ WoT) {
  __shared__ float t[64][65];
  const int k0 = blockIdx.x * 64, n0 = blockIdx.y * 64;
  const int r = threadIdx.x >> 4, c4 = threadIdx.x & 15;
#pragma unroll
  for (int i = 0; i < 4; ++i) {
    float4 v = *(const float4*)&Wo[(size_t)(k0 + r + 16 * i) * D_ + n0 + c4 * 4];
    t[r + 16 * i][c4 * 4 + 0] = v.x;
    t[r + 16 * i][c4 * 4 + 1] = v.y;
    t[r + 16 * i][c4 * 4 + 2] = v.z;
    t[r + 16 * i][c4 * 4 + 3] = v.w;
  }
  __syncthreads();
  const int n = threadIdx.x >> 2, kc = threadIdx.x & 3;
  union {
    unsigned short u[16];
    uint4 v[2];
  } pk;
#pragma unroll
  for (int j = 0; j < 16; ++j) pk.u[j] = f2bf(t[kc * 16 + j][n]);
  unsigned short* op = WoT + (size_t)(n0 + n) * D_ + k0 + kc * 16;
  *(uint4*)op = pk.v[0];
  *(uint4*)(op + 8) = pk.v[1];
}

// ---------------------------------------------------------------------------
// Kernel 3b: out[4096,1024] = ctx_bf16 @ WoT^T + bo, bf16 MFMA, fp32 out.
// ---------------------------------------------------------------------------
__global__ __launch_bounds__(256) void out_gemm_mfma(
    const unsigned short* __restrict__ A,
    const unsigned short* __restrict__ BT,
    const float* __restrict__ bo, float* __restrict__ C) {
  __shared__ __align__(16) unsigned short As[128 * 64];
  __shared__ __align__(16) unsigned short Bs[128 * 64];

  const int tid = threadIdx.x;
  const int w = tid >> 6, l = tid & 63;
  const int ll = l & 15, lg = l >> 4;
  const int wr = w >> 1, wc = w & 1;
  const int m0 = blockIdx.y * 128, n0 = blockIdx.x * 128;

  const int srow = l >> 3;
  const int sslot = (l & 7) ^ srow;
  const int g_off = sslot * 8;

  f32x4 acc[4][4];
#pragma unroll
  for (int mt = 0; mt < 4; ++mt)
#pragma unroll
    for (int nt = 0; nt < 4; ++nt) acc[mt][nt] = (f32x4){0.f, 0.f, 0.f, 0.f};

  for (int k0 = 0; k0 < D_; k0 += 64) {
    __syncthreads();
#pragma unroll
    for (int c = 0; c < 4; ++c) {
      const int row = c * 32 + w * 8 + srow;
      load16_lds(A + (size_t)(m0 + row) * D_ + k0 + g_off,
                 (char*)As + c * 4096 + w * 1024);
      load16_lds(BT + (size_t)(n0 + row) * D_ + k0 + g_off,
                 (char*)Bs + c * 4096 + w * 1024);
    }
    __syncthreads();

#pragma unroll
    for (int half = 0; half < 2; ++half) {
      bf16x8 af[4], bfr[4];
#pragma unroll
      for (int mt = 0; mt < 4; ++mt) {
        const int row = wr * 64 + mt * 16 + ll;
        af[mt] = *(const bf16x8*)((const char*)As + row * 128 +
                                  (((half * 4 + lg) ^ (row & 7)) << 4));
      }
#pragma unroll
      for (int nt = 0; nt < 4; ++nt) {
        const int rowb = wc * 64 + nt * 16 + ll;
        bfr[nt] = *(const bf16x8*)((const char*)Bs + rowb * 128 +
                                   (((half * 4 + lg) ^ (rowb & 7)) << 4));
      }
#pragma unroll
      for (int mt = 0; mt < 4; ++mt)
#pragma unroll
        for (int nt = 0; nt < 4; ++nt)
          acc[mt][nt] = __builtin_amdgcn_mfma_f32_16x16x32_bf16(
              af[mt], bfr[nt], acc[mt][nt], 0, 0, 0);
    }
  }

#pragma unroll
  for (int nt = 0; nt < 4; ++nt) {
    const int col = n0 + wc * 64 + nt * 16 + ll;
    const float bv = bo[col];
#pragma unroll
    for (int mt = 0; mt < 4; ++mt) {
      const int row0 = m0 + wr * 64 + mt * 16 + lg * 4;
#pragma unroll
      for (int r = 0; r < 4; ++r)
        C[(size_t)(row0 + r) * D_ + col] = acc[mt][nt][r] + bv;
    }
  }
}

// ---------------------------------------------------------------------------
extern "C" void kernel_launch(void* const* d_in, const int* in_sizes, int n_in,
                              void* d_out, int out_size, void* d_ws,
                              size_t ws_size, hipStream_t stream) {
  const float* q = (const float*)d_in[0];
  const float* k = (const float*)d_in[1];
  const float* v = (const float*)d_in[2];
  const float* Wq1 = (const float*)d_in[3];
  const float* bq1 = (const float*)d_in[4];
  const float* Wq2 = (const float*)d_in[5];
  const float* bq2 = (const float*)d_in[6];
  const float* Wk1 = (const float*)d_in[7];
  const float* bk1 = (const float*)d_in[8];
  const float* Wk2 = (const float*)d_in[9];
  const float* bk2 = (const float*)d_in[10];
  const float* Wv1 = (const float*)d_in[11];
  const float* bv1 = (const float*)d_in[12];
  const float* Wv2 = (const float*)d_in[13];
  const float* bv2 = (const float*)d_in[14];
  const float* Wo = (const float*)d_in[15];
  const float* bo = (const float*)d_in[16];
  float* out = (float*)d_out;

  const size_t TEN = (size_t)B_ * H_ * S_ * DK_;  // 4,194,304 elements
  char* ws = (char*)d_ws;
  unsigned short* qhb = (unsigned short*)ws;              // bf16 [BH,S,DK]
  unsigned short* khb = (unsigned short*)(ws + TEN * 2);  // bf16 [BH,S,DK]
  unsigned short* vtb = (unsigned short*)(ws + TEN * 4);  // bf16 [BH,DK,S]
  unsigned short* ctxb = (unsigned short*)(ws + TEN * 6); // bf16 [B,S,D]
  unsigned short* wot = (unsigned short*)(ws + TEN * 8);  // bf16 [N,K] = Wo^T

  const float cs = 0.125f * 1.44269504088896340736f;  // 1/sqrt(64) * log2(e)
  quantum_fused<<<dim3(16, 32, 3), 256, 0, stream>>>(
      q, k, v, Wq1, bq1, Wq2, bq2, Wk1, bk1, Wk2, bk2, Wv1, bv1, Wv2, bv2,
      qhb, khb, vtb, cs);
  wo_transpose<<<dim3(16, 16), 256, 0, stream>>>(Wo, wot);

  attn_kernel<<<dim3(32, 16), 256, 0, stream>>>(qhb, khb, vtb, ctxb);

  out_gemm_mfma<<<dim3(8, 32), 256, 0, stream>>>(ctxb, wot, bo, out);
}

// Round 9
// 116.141 us; speedup vs baseline: 1.9105x; 1.0506x over previous
//
#include <hip/hip_runtime.h>

#define B_ 2
#define S_ 2048
#define D_ 1024
#define H_ 16
#define DK_ 64

typedef float f32x4 __attribute__((ext_vector_type(4)));
typedef float f32x16 __attribute__((ext_vector_type(16)));
typedef short bf16x8 __attribute__((ext_vector_type(8)));

static __device__ __forceinline__ unsigned short f2bf(float f) {
  unsigned u = __float_as_uint(f);
  unsigned r = (u + 0x7FFFu + ((u >> 16) & 1u)) >> 16;
  return (unsigned short)r;
}

static __device__ __forceinline__ unsigned cvtpk_bf16(float lo, float hi) {
  unsigned r;
  asm("v_cvt_pk_bf16_f32 %0, %1, %2" : "=v"(r) : "v"(lo), "v"(hi));
  return r;
}

static __device__ __forceinline__ void load16_lds(const void* g, void* lds) {
  __builtin_amdgcn_global_load_lds(
      (const __attribute__((address_space(1))) unsigned int*)g,
      (__attribute__((address_space(3))) unsigned int*)lds, 16, 0, 0);
}

// gather 8 consecutive C-rows of this lane's owned column from crow-scattered
// accumulator regs p[0..7]; returns the 8 bf16 packed (A-frag k-slice).
static __device__ __forceinline__ bf16x8 make_pa8(const float* p, int hi) {
  unsigned x1 = cvtpk_bf16(p[0], p[1]);
  unsigned x2 = cvtpk_bf16(p[2], p[3]);
  unsigned y1 = cvtpk_bf16(p[4], p[5]);
  unsigned y2 = cvtpk_bf16(p[6], p[7]);
  unsigned sx1 = (unsigned)__shfl_xor((int)x1, 32);
  unsigned sx2 = (unsigned)__shfl_xor((int)x2, 32);
  unsigned sy1 = (unsigned)__shfl_xor((int)y1, 32);
  unsigned sy2 = (unsigned)__shfl_xor((int)y2, 32);
  union {
    unsigned u[4];
    bf16x8 v;
  } pa;
  pa.u[0] = hi ? sy1 : x1;
  pa.u[1] = hi ? sy2 : x2;
  pa.u[2] = hi ? y1 : sx1;
  pa.u[3] = hi ? y2 : sx2;
  return pa.v;
}

static __device__ __forceinline__ float tanh_fast(float x) {
  float xc = fminf(fmaxf(x, -9.0f), 9.0f);
  float e = exp2f(xc * 2.88539008177792681472f);  // 2*log2(e)
  return (e - 1.0f) / (e + 1.0f);
}

// ---------------------------------------------------------------------------
// Kernel 1: fused MFMA quantum transform for q, k, v (blockIdx.z selects).
// ---------------------------------------------------------------------------
__global__ __launch_bounds__(256) void quantum_fused(
    const float* __restrict__ xq, const float* __restrict__ xk,
    const float* __restrict__ xv,
    const float* __restrict__ Wq1, const float* __restrict__ bq1,
    const float* __restrict__ Wq2, const float* __restrict__ bq2,
    const float* __restrict__ Wk1, const float* __restrict__ bk1,
    const float* __restrict__ Wk2, const float* __restrict__ bk2,
    const float* __restrict__ Wv1, const float* __restrict__ bv1,
    const float* __restrict__ Wv2, const float* __restrict__ bv2,
    unsigned short* __restrict__ qhb, unsigned short* __restrict__ khb,
    unsigned short* __restrict__ vtb, float qscale) {
  const int tid = threadIdx.x;
  const int w = tid >> 6;
  const int l = tid & 63;
  const int lq = l & 31;
  const int hi = l >> 5;
  const int bh = blockIdx.y;
  const int b = bh >> 4, h = bh & 15;
  const int s0w = blockIdx.x * 128 + w * 32;

  const float* x;
  const float* W1;
  const float* b1;
  const float* W2;
  const float* b2;
  unsigned short* outp;
  float scale = 1.0f;
  int vmode = 0;
  if (blockIdx.z == 0) {
    x = xq; W1 = Wq1; b1 = bq1; W2 = Wq2; b2 = bq2; outp = qhb;
    scale = qscale;
  } else if (blockIdx.z == 1) {
    x = xk; W1 = Wk1; b1 = bk1; W2 = Wk2; b2 = bk2; outp = khb;
  } else {
    x = xv; W1 = Wv1; b1 = bv1; W2 = Wv2; b2 = bv2; outp = vtb;
    vmode = 1;
  }

  bf16x8 w1f[2][4];
#pragma unroll
  for (int ca = 0; ca < 2; ++ca)
#pragma unroll
    for (int kc = 0; kc < 4; ++kc) {
      const float* wp = W1 + (size_t)(kc * 16 + hi * 8) * 64 + ca * 32 + lq;
      union {
        unsigned u[4];
        bf16x8 v;
      } ww;
#pragma unroll
      for (int jj = 0; jj < 4; ++jj)
        ww.u[jj] = cvtpk_bf16(wp[(2 * jj) * 64], wp[(2 * jj + 1) * 64]);
      w1f[ca][kc] = ww.v;
    }

  const float* xrow = x + (((size_t)b * S_ + s0w + lq) * H_ + h) * DK_;
  bf16x8 xf[4];
#pragma unroll
  for (int kc = 0; kc < 4; ++kc) {
    float4 f0 = *(const float4*)(xrow + kc * 16 + hi * 8);
    float4 f1 = *(const float4*)(xrow + kc * 16 + hi * 8 + 4);
    union {
      unsigned u[4];
      bf16x8 v;
    } xx;
    xx.u[0] = cvtpk_bf16(f0.x, f0.y);
    xx.u[1] = cvtpk_bf16(f0.z, f0.w);
    xx.u[2] = cvtpk_bf16(f1.x, f1.y);
    xx.u[3] = cvtpk_bf16(f1.z, f1.w);
    xf[kc] = xx.v;
  }

  f32x16 acc1[2];
#pragma unroll
  for (int ca = 0; ca < 2; ++ca)
#pragma unroll
    for (int r = 0; r < 16; ++r)
      acc1[ca][r] = b1[ca * 32 + (r & 3) + 8 * (r >> 2) + 4 * hi];
#pragma unroll
  for (int kc = 0; kc < 4; ++kc) {
    acc1[0] = __builtin_amdgcn_mfma_f32_32x32x16_bf16(w1f[0][kc], xf[kc], acc1[0], 0, 0, 0);
    acc1[1] = __builtin_amdgcn_mfma_f32_32x32x16_bf16(w1f[1][kc], xf[kc], acc1[1], 0, 0, 0);
  }

  float t0[16], t1[16];
#pragma unroll
  for (int r = 0; r < 16; ++r) {
    t0[r] = tanh_fast(acc1[0][r]);
    t1[r] = tanh_fast(acc1[1][r]);
  }

  bf16x8 af[4];
  af[0] = make_pa8(&t0[0], hi);
  af[1] = make_pa8(&t0[8], hi);
  af[2] = make_pa8(&t1[0], hi);
  af[3] = make_pa8(&t1[8], hi);

  bf16x8 w2f[2][4];
#pragma unroll
  for (int nb = 0; nb < 2; ++nb)
#pragma unroll
    for (int kc = 0; kc < 4; ++kc) {
      const float* wp = W2 + (size_t)(kc * 16 + hi * 8) * 64 + nb * 32 + lq;
      union {
        unsigned u[4];
        bf16x8 v;
      } ww;
#pragma unroll
      for (int jj = 0; jj < 4; ++jj)
        ww.u[jj] = cvtpk_bf16(wp[(2 * jj) * 64], wp[(2 * jj + 1) * 64]);
      w2f[nb][kc] = ww.v;
    }

  f32x16 acc2[2];
#pragma unroll
  for (int nb = 0; nb < 2; ++nb)
#pragma unroll
    for (int r = 0; r < 16; ++r)
      acc2[nb][r] = b2[nb * 32 + (r & 3) + 8 * (r >> 2) + 4 * hi];
#pragma unroll
  for (int kc = 0; kc < 4; ++kc) {
    acc2[0] = __builtin_amdgcn_mfma_f32_32x32x16_bf16(af[kc], w2f[0][kc], acc2[0], 0, 0, 0);
    acc2[1] = __builtin_amdgcn_mfma_f32_32x32x16_bf16(af[kc], w2f[1][kc], acc2[1], 0, 0, 0);
  }

  if (!vmode) {
#pragma unroll
    for (int nb = 0; nb < 2; ++nb)
#pragma unroll
      for (int r = 0; r < 16; ++r) {
        const int s = s0w + (r & 3) + 8 * (r >> 2) + 4 * hi;
        outp[((size_t)bh * S_ + s) * DK_ + nb * 32 + lq] =
            f2bf(acc2[nb][r] * scale);
      }
  } else {
#pragma unroll
    for (int nb = 0; nb < 2; ++nb) {
      float yv[16];
#pragma unroll
      for (int r = 0; r < 16; ++r) yv[r] = acc2[nb][r];
      const size_t rowb = ((size_t)bh * DK_ + nb * 32 + lq) * S_;
      *(bf16x8*)(outp + rowb + s0w + hi * 8) = make_pa8(&yv[0], hi);
      *(bf16x8*)(outp + rowb + s0w + 16 + hi * 8) = make_pa8(&yv[8], hi);
    }
  }
}

// ---------------------------------------------------------------------------
// Kernel 2: MFMA flash attention, swapped-QK^T 32x32x16.
// Triple-buffered K/V staging via global_load_lds (pre-swizzled source),
// depth-2 prefetch, counted vmcnt(4) + raw s_barrier (never drain to 0 in
// main loop). setprio(1) around MFMA clusters. grid (32 bh, 16 q-blocks).
// ---------------------------------------------------------------------------
__global__ __launch_bounds__(256) void attn_kernel(
    const unsigned short* __restrict__ qhb,
    const unsigned short* __restrict__ khb,
    const unsigned short* __restrict__ vtb,
    unsigned short* __restrict__ ctxb) {
  __shared__ __align__(16) unsigned short ks_u[3][64 * 64];  // 3-buf K tiles
  __shared__ __align__(16) unsigned short vs_u[3][64 * 64];  // 3-buf V^T tiles

  const int tid = threadIdx.x;
  const int w = tid >> 6;
  const int l = tid & 63;
  const int lq = l & 31;
  const int hi = l >> 5;
  const int bh = blockIdx.x;
  const int b = bh >> 4, h = bh & 15;
  const int q0 = blockIdx.y * 128 + w * 32;

  // Q fragments for the whole kernel (pre-scaled by 1/8*log2e)
  const unsigned short* qp = qhb + ((size_t)bh * S_ + q0 + lq) * DK_ + hi * 8;
  bf16x8 qf[4];
#pragma unroll
  for (int kc = 0; kc < 4; ++kc) qf[kc] = *(const bf16x8*)(qp + kc * 16);

  f32x16 o0 = {}, o1 = {};
  float m_ = -1e30f, l_ = 0.f;

  const unsigned short* kgbase = khb + (size_t)bh * S_ * DK_;
  const unsigned short* vgbase = vtb + (size_t)bh * DK_ * S_;
  // staging: wave w moves LDS rows [w*16, w*16+16). Linear LDS dest
  // (wave base + lane*16); global source pre-swizzled (slot^row within 8).
  const int r0 = w * 16 + (l >> 3);
  const int sl8 = ((l & 7) ^ (l >> 3)) * 8;  // elem offset within row

#define STAGE(BUF, TT)                                                        \
  {                                                                           \
    const int tb = (TT)*64;                                                   \
    char* kb = (char*)ks_u[BUF] + w * 2048;                                   \
    char* vb = (char*)vs_u[BUF] + w * 2048;                                   \
    load16_lds(kgbase + (size_t)(tb + r0) * DK_ + sl8, kb);                   \
    load16_lds(kgbase + (size_t)(tb + r0 + 8) * DK_ + sl8, kb + 1024);        \
    load16_lds(vgbase + (size_t)r0 * S_ + tb + sl8, vb);                      \
    load16_lds(vgbase + (size_t)(r0 + 8) * S_ + tb + sl8, vb + 1024);         \
  }

  STAGE(0, 0)
  STAGE(1, 1)

  for (int t = 0; t < 32; ++t) {
    // wait own tile-t loads (oldest 4); keep tile t+1's 4 in flight
    if (t < 31) {
      asm volatile("s_waitcnt vmcnt(4)" ::: "memory");
    } else {
      asm volatile("s_waitcnt vmcnt(0)" ::: "memory");
    }
    __builtin_amdgcn_sched_barrier(0);
    __builtin_amdgcn_s_barrier();
    __builtin_amdgcn_sched_barrier(0);

    const int cur = t % 3;
    const char* ksP = (const char*)ks_u[cur];
    const char* vsP = (const char*)vs_u[cur];
    if (t < 30) STAGE((t + 2) % 3, t + 2)  // overwrites tile t-1's buffer: safe

    // ---- QK^T: S^T[k][q=lq] ----
    f32x16 s0 = {}, s1 = {};
    __builtin_amdgcn_s_setprio(1);
#pragma unroll
    for (int kc = 0; kc < 4; ++kc) {
      const int slot = kc * 2 + hi;
      bf16x8 k0 = *(const bf16x8*)(ksP + lq * 128 + ((slot ^ (lq & 7)) << 4));
      bf16x8 k1 = *(const bf16x8*)(ksP + (32 + lq) * 128 + ((slot ^ (lq & 7)) << 4));
      s0 = __builtin_amdgcn_mfma_f32_32x32x16_bf16(k0, qf[kc], s0, 0, 0, 0);
      s1 = __builtin_amdgcn_mfma_f32_32x32x16_bf16(k1, qf[kc], s1, 0, 0, 0);
    }
    __builtin_amdgcn_s_setprio(0);

    // ---- lane-local online softmax with defer-max (THR=8) ----
    float pmax = fmaxf(fmaxf(s0[0], s0[1]), fmaxf(s0[2], s0[3]));
#pragma unroll
    for (int i = 4; i < 16; i += 4)
      pmax = fmaxf(pmax, fmaxf(fmaxf(s0[i], s0[i + 1]), fmaxf(s0[i + 2], s0[i + 3])));
#pragma unroll
    for (int i = 0; i < 16; i += 4)
      pmax = fmaxf(pmax, fmaxf(fmaxf(s1[i], s1[i + 1]), fmaxf(s1[i + 2], s1[i + 3])));
    pmax = fmaxf(pmax, __shfl_xor(pmax, 32));

    if (!__all(pmax <= m_ + 8.0f)) {
      const float mnew = fmaxf(m_, pmax);
      const float scl = exp2f(m_ - mnew);
      m_ = mnew;
      l_ *= scl;
#pragma unroll
      for (int r = 0; r < 16; ++r) {
        const float sr = __shfl(scl, ((r & 3) + 8 * (r >> 2)) + 4 * hi);
        o0[r] *= sr;
        o1[r] *= sr;
      }
    }

    // exp2 in place (P values)
#pragma unroll
    for (int i = 0; i < 16; ++i) s0[i] = exp2f(s0[i] - m_);
#pragma unroll
    for (int i = 0; i < 16; ++i) s1[i] = exp2f(s1[i] - m_);
    {
      float t0a = 0.f, t1a = 0.f, t2a = 0.f, t3a = 0.f;
#pragma unroll
      for (int i = 0; i < 16; i += 4) {
        t0a += s0[i] + s1[i];
        t1a += s0[i + 1] + s1[i + 1];
        t2a += s0[i + 2] + s1[i + 2];
        t3a += s0[i + 3] + s1[i + 3];
      }
      float ps = (t0a + t1a) + (t2a + t3a);
      ps += __shfl_xor(ps, 32);
      l_ += ps;
    }

    // ---- P -> A-frags + PV ----
    float pv[8];
    union {
      unsigned u[4];
      bf16x8 v;
    } pa;

#define PV_STEP(SARR, CC, CIDX)                                               \
  {                                                                           \
    _Pragma("unroll") for (int j = 0; j < 8; ++j) pv[j] = SARR[(CC)*8 + j];   \
    pa.v = make_pa8(pv, hi);                                                  \
    const int slot = (CIDX)*2 + hi;                                           \
    bf16x8 v0 = *(const bf16x8*)(vsP + lq * 128 + ((slot ^ (lq & 7)) << 4));  \
    bf16x8 v1 = *(const bf16x8*)(vsP + (32 + lq) * 128 + ((slot ^ (lq & 7)) << 4)); \
    o0 = __builtin_amdgcn_mfma_f32_32x32x16_bf16(pa.v, v0, o0, 0, 0, 0);      \
    o1 = __builtin_amdgcn_mfma_f32_32x32x16_bf16(pa.v, v1, o1, 0, 0, 0);      \
  }

    __builtin_amdgcn_s_setprio(1);
    PV_STEP(s0, 0, 0)
    PV_STEP(s0, 1, 1)
    PV_STEP(s1, 0, 2)
    PV_STEP(s1, 1, 3)
    __builtin_amdgcn_s_setprio(0);
#undef PV_STEP
  }
#undef STAGE

  // ---- epilogue: O[q][d] / l_[q], bf16 store ----
  const float linv = 1.0f / l_;
#pragma unroll
  for (int r = 0; r < 16; ++r) {
    const int crow = ((r & 3) + 8 * (r >> 2)) + 4 * hi;
    const float lr = __shfl(linv, crow);
    const int qg = q0 + crow;
    const size_t base = ((size_t)b * S_ + qg) * D_ + h * DK_;
    ctxb[base + lq] = f2bf(o0[r] * lr);
    ctxb[base + 32 + lq] = f2bf(o1[r] * lr);
  }
}

// ---------------------------------------------------------------------------
// Kernel 3a: Wo fp32 [K][N] -> WoT bf16 [N][K]
// ---------------------------------------------------------------------------
__global__ __launch_bounds__(256) void wo_transpose(
    const float* __restrict__ Wo, unsigned short* __restrict__ WoT) {
  __shared__ float t[64][65];
  const int k0 = blockIdx.x * 64, n0 = blockIdx.y * 64;
  const int r = threadIdx.x >> 4, c4 = threadIdx.x & 15;
#pragma unroll
  for (int i = 0; i < 4; ++i) {
    float4 v = *(const float4*)&Wo[(size_t)(k0 + r + 16 * i) * D_ + n0 + c4 * 4];
    t[r + 16 * i][c4 * 4 + 0] = v.x;
    t[r + 16 * i][c4 * 4 + 1] = v.y;
    t[r + 16 * i][c4 * 4 + 2] = v.z;
    t[r + 16 * i][c4 * 4 + 3] = v.w;
  }
  __syncthreads();
  const int n = threadIdx.x >> 2, kc = threadIdx.x & 3;
  union {
    unsigned short u[16];
    uint4 v[2];
  } pk;
#pragma unroll
  for (int j = 0; j < 16; ++j) pk.u[j] = f2bf(t[kc * 16 + j][n]);
  unsigned short* op = WoT + (size_t)(n0 + n) * D_ + k0 + kc * 16;
  *(uint4*)op = pk.v[0];
  *(uint4*)(op + 8) = pk.v[1];
}

// ---------------------------------------------------------------------------
// Kernel 3b: out[4096,1024] = ctx_bf16 @ WoT^T + bo, bf16 MFMA, fp32 out.
// Triple-buffered staging, counted vmcnt(8) + raw s_barrier (same schedule
// as attn). grid (8, 32), 256 threads.
// ---------------------------------------------------------------------------
__global__ __launch_bounds__(256) void out_gemm_mfma(
    const unsigned short* __restrict__ A,
    const unsigned short* __restrict__ BT,
    const float* __restrict__ bo, float* __restrict__ C) {
  __shared__ __align__(16) unsigned short As[3][128 * 64];
  __shared__ __align__(16) unsigned short Bs[3][128 * 64];

  const int tid = threadIdx.x;
  const int w = tid >> 6, l = tid & 63;
  const int ll = l & 15, lg = l >> 4;
  const int wr = w >> 1, wc = w & 1;
  const int m0 = blockIdx.y * 128, n0 = blockIdx.x * 128;

  const int srow = l >> 3;
  const int sslot = (l & 7) ^ srow;
  const int g_off = sslot * 8;

  f32x4 acc[4][4];
#pragma unroll
  for (int mt = 0; mt < 4; ++mt)
#pragma unroll
    for (int nt = 0; nt < 4; ++nt) acc[mt][nt] = (f32x4){0.f, 0.f, 0.f, 0.f};

#define STAGE_G(BUF, KT)                                                      \
  {                                                                           \
    const int k0e = (KT)*64;                                                  \
    _Pragma("unroll") for (int c = 0; c < 4; ++c) {                           \
      const int row = c * 32 + w * 8 + srow;                                  \
      load16_lds(A + (size_t)(m0 + row) * D_ + k0e + g_off,                   \
                 (char*)As[BUF] + c * 4096 + w * 1024);                       \
      load16_lds(BT + (size_t)(n0 + row) * D_ + k0e + g_off,                  \
                 (char*)Bs[BUF] + c * 4096 + w * 1024);                       \
    }                                                                         \
  }

  STAGE_G(0, 0)
  STAGE_G(1, 1)

  for (int kt = 0; kt < 16; ++kt) {
    if (kt < 15) {
      asm volatile("s_waitcnt vmcnt(8)" ::: "memory");
    } else {
      asm volatile("s_waitcnt vmcnt(0)" ::: "memory");
    }
    __builtin_amdgcn_sched_barrier(0);
    __builtin_amdgcn_s_barrier();
    __builtin_amdgcn_sched_barrier(0);

    const int cur = kt % 3;
    if (kt < 14) STAGE_G((kt + 2) % 3, kt + 2)

#pragma unroll
    for (int half = 0; half < 2; ++half) {
      bf16x8 af[4], bfr[4];
#pragma unroll
      for (int mt = 0; mt < 4; ++mt) {
        const int row = wr * 64 + mt * 16 + ll;
        af[mt] = *(const bf16x8*)((const char*)As[cur] + row * 128 +
                                  (((half * 4 + lg) ^ (row & 7)) << 4));
      }
#pragma unroll
      for (int nt = 0; nt < 4; ++nt) {
        const int rowb = wc * 64 + nt * 16 + ll;
        bfr[nt] = *(const bf16x8*)((const char*)Bs[cur] + rowb * 128 +
                                   (((half * 4 + lg) ^ (rowb & 7)) << 4));
      }
      __builtin_amdgcn_s_setprio(1);
#pragma unroll
      for (int mt = 0; mt < 4; ++mt)
#pragma unroll
        for (int nt = 0; nt < 4; ++nt)
          acc[mt][nt] = __builtin_amdgcn_mfma_f32_16x16x32_bf16(
              af[mt], bfr[nt], acc[mt][nt], 0, 0, 0);
      __builtin_amdgcn_s_setprio(0);
    }
  }
#undef STAGE_G

#pragma unroll
  for (int nt = 0; nt < 4; ++nt) {
    const int col = n0 + wc * 64 + nt * 16 + ll;
    const float bv = bo[col];
#pragma unroll
    for (int mt = 0; mt < 4; ++mt) {
      const int row0 = m0 + wr * 64 + mt * 16 + lg * 4;
#pragma unroll
      for (int r = 0; r < 4; ++r)
        C[(size_t)(row0 + r) * D_ + col] = acc[mt][nt][r] + bv;
    }
  }
}

// ---------------------------------------------------------------------------
extern "C" void kernel_launch(void* const* d_in, const int* in_sizes, int n_in,
                              void* d_out, int out_size, void* d_ws,
                              size_t ws_size, hipStream_t stream) {
  const float* q = (const float*)d_in[0];
  const float* k = (const float*)d_in[1];
  const float* v = (const float*)d_in[2];
  const float* Wq1 = (const float*)d_in[3];
  const float* bq1 = (const float*)d_in[4];
  const float* Wq2 = (const float*)d_in[5];
  const float* bq2 = (const float*)d_in[6];
  const float* Wk1 = (const float*)d_in[7];
  const float* bk1 = (const float*)d_in[8];
  const float* Wk2 = (const float*)d_in[9];
  const float* bk2 = (const float*)d_in[10];
  const float* Wv1 = (const float*)d_in[11];
  const float* bv1 = (const float*)d_in[12];
  const float* Wv2 = (const float*)d_in[13];
  const float* bv2 = (const float*)d_in[14];
  const float* Wo = (const float*)d_in[15];
  const float* bo = (const float*)d_in[16];
  float* out = (float*)d_out;

  const size_t TEN = (size_t)B_ * H_ * S_ * DK_;  // 4,194,304 elements
  char* ws = (char*)d_ws;
  unsigned short* qhb = (unsigned short*)ws;              // bf16 [BH,S,DK]
  unsigned short* khb = (unsigned short*)(ws + TEN * 2);  // bf16 [BH,S,DK]
  unsigned short* vtb = (unsigned short*)(ws + TEN * 4);  // bf16 [BH,DK,S]
  unsigned short* ctxb = (unsigned short*)(ws + TEN * 6); // bf16 [B,S,D]
  unsigned short* wot = (unsigned short*)(ws + TEN * 8);  // bf16 [N,K] = Wo^T

  const float cs = 0.125f * 1.44269504088896340736f;  // 1/sqrt(64) * log2(e)
  quantum_fused<<<dim3(16, 32, 3), 256, 0, stream>>>(
      q, k, v, Wq1, bq1, Wq2, bq2, Wk1, bk1, Wk2, bk2, Wv1, bv1, Wv2, bv2,
      qhb, khb, vtb, cs);
  wo_transpose<<<dim3(16, 16), 256, 0, stream>>>(Wo, wot);

  attn_kernel<<<dim3(32, 16), 256, 0, stream>>>(qhb, khb, vtb, ctxb);

  out_gemm_mfma<<<dim3(8, 32), 256, 0, stream>>>(ctxb, wot, bo, out);
}